// Round 3
// baseline (336.690 us; speedup 1.0000x reference)
//
#include <hip/hip_runtime.h>
#include <hip/hip_bf16.h>
#include <stdint.h>

// Problem constants
#define D_ 1024
#define H_ 16
#define DH_ 64
#define F_ 4096
#define B_ 4
#define L_ 2048
#define MTOK 8192   // B_*L_

typedef __attribute__((ext_vector_type(8))) short bf16x8;
typedef __attribute__((ext_vector_type(4))) float f32x4;

__device__ __forceinline__ short f2bf(float f) {
  uint32_t u = __float_as_uint(f);
  uint32_t r = (u + 0x7FFFu + ((u >> 16) & 1u)) >> 16;
  return (short)(uint16_t)r;
}
__device__ __forceinline__ float bf2f(short s) {
  return __uint_as_float(((uint32_t)(uint16_t)s) << 16);
}

__device__ __forceinline__ void gload_lds16(const short* g, short* l) {
  __builtin_amdgcn_global_load_lds(
      (const __attribute__((address_space(1))) void*)g,
      (__attribute__((address_space(3))) void*)l,
      16, 0, 0);
}

// ---------------- f32 -> bf16 conversion (with optional scale) ----------------
__global__ void __launch_bounds__(256) convert_bf16(
    const float* __restrict__ src, short* __restrict__ dst, long n, float scale) {
  long i = ((long)blockIdx.x * 256 + threadIdx.x) * 4;
  long stride = (long)gridDim.x * 1024;
  for (; i < n; i += stride) {
    float4 f = *(const float4*)(src + i);
    short4 o;
    o.x = f2bf(f.x * scale);
    o.y = f2bf(f.y * scale);
    o.z = f2bf(f.z * scale);
    o.w = f2bf(f.w * scale);
    *(short4*)(dst + i) = o;
  }
}

// =====================================================================
// Deep-pipelined GEMM: C[M,N] = A[M,K] @ B[N,K]^T (+bias, relu)
// BN=256, BM=BMT*128, BK=64, 8 waves (2M x 4N), wave tile (BMT*64) x 64.
// 4 phases per K-tile = 4 C-quadrants (mh,nh): (0,0),(0,1),(1,1),(1,0).
// ds_reads run ONE quadrant ahead (counted lgkmcnt) so LDS service
// overlaps MFMA. Stages (global_load_lds) spread at p2/p3 targeting
// tile g+2; single counted vmcnt gate per K-tile at p3.
// T2 swizzle: linear LDS dest, pre-swizzled global source, swizzled read.
// T1 XCD swizzle on flat block id (grid size must be multiple of 8).
// =====================================================================
#define BAR   __builtin_amdgcn_s_barrier()
#define SB0   __builtin_amdgcn_sched_barrier(0)
#define PRIO1 __builtin_amdgcn_s_setprio(1)
#define PRIO0 __builtin_amdgcn_s_setprio(0)

#define RD_A(mh_, par_) do {                                                  \
  const short* bp = lds + (par_) * BUF + wm * AH;                             \
  _Pragma("unroll")                                                           \
  for (int m2 = 0; m2 < MH; m2++) {                                           \
    const int r = ((mh_) * MH + m2) * 16 + l15;                               \
    _Pragma("unroll")                                                         \
    for (int ks = 0; ks < 2; ks++)                                            \
      aF[mh_][m2][ks] =                                                       \
          *(const bf16x8*)(bp + r * 64 + (((ks * 4 + l4) ^ (r & 7)) << 3));   \
  } } while (0)

#define RD_B(nh_, par_) do {                                                  \
  const short* bp = lds + (par_) * BUF + BM * 64 + (wn >> 1) * 8192;          \
  _Pragma("unroll")                                                           \
  for (int n2 = 0; n2 < 2; n2++) {                                            \
    const int r = (wn & 1) * 64 + ((nh_) * 2 + n2) * 16 + l15;                \
    _Pragma("unroll")                                                         \
    for (int ks = 0; ks < 2; ks++)                                            \
      bF[nh_][n2][ks] =                                                       \
          *(const bf16x8*)(bp + r * 64 + (((ks * 4 + l4) ^ (r & 7)) << 3));   \
  } } while (0)

#define QUAD(mh_, nh_) do {                                                   \
  _Pragma("unroll")                                                           \
  for (int ks = 0; ks < 2; ks++)                                              \
    _Pragma("unroll")                                                         \
    for (int m2 = 0; m2 < MH; m2++)                                           \
      _Pragma("unroll")                                                       \
      for (int n2 = 0; n2 < 2; n2++)                                          \
        acc[(mh_) * MH + m2][(nh_) * 2 + n2] =                                \
            __builtin_amdgcn_mfma_f32_16x16x32_bf16(                          \
                aF[mh_][m2][ks], bF[nh_][n2][ks],                             \
                acc[(mh_) * MH + m2][(nh_) * 2 + n2], 0, 0, 0);               \
} while (0)

#define ITERG(g_, PAR_) do {                                                  \
  /* p0: read both B halves of tile g (nh0 first), MFMA q(0,0) */             \
  RD_B(0, PAR_); RD_B(1, PAR_);                                               \
  asm volatile("s_waitcnt lgkmcnt(4)" ::: "memory"); SB0;                     \
  PRIO1; QUAD(0, 0); PRIO0; SB0;                                              \
  BAR;                                                                        \
  /* p1: read A-mh1 of tile g, MFMA q(0,1) */                                 \
  RD_A(1, PAR_);                                                              \
  asm volatile("s_waitcnt lgkmcnt(%0)" :: "i"(2 * MH) : "memory"); SB0;       \
  PRIO1; QUAD(0, 1); PRIO0; SB0;                                              \
  BAR;                                                                        \
  /* p2: stage tile g+2 (A-h0, B-h0), MFMA q(1,1) */                          \
  if ((g_) + 2 < NTILE) { stA((g_) + 2, 0, PAR_); stB((g_) + 2, 0, PAR_); }   \
  SB0;                                                                        \
  asm volatile("s_waitcnt lgkmcnt(0)" ::: "memory"); SB0;                     \
  PRIO1; QUAD(1, 1); PRIO0; SB0;                                              \
  BAR;                                                                        \
  /* p3: vmcnt gate, read next tile's A-mh0, stage g+2 (A-h1,B-h1), q(1,0) */ \
  if ((g_) + 1 < NTILE) {                                                     \
    if ((g_) + 2 < NTILE) {                                                   \
      asm volatile("s_waitcnt vmcnt(%0)" :: "i"(VGATE) : "memory");           \
    } else {                                                                  \
      asm volatile("s_waitcnt vmcnt(0)" ::: "memory");                        \
    }                                                                         \
    BAR; SB0;                                                                 \
    RD_A(0, 1 - (PAR_));                                                      \
  }                                                                           \
  if ((g_) + 2 < NTILE) { stA((g_) + 2, 1, PAR_); stB((g_) + 2, 1, PAR_); }   \
  SB0;                                                                        \
  PRIO1; QUAD(1, 0); PRIO0; SB0;                                              \
  BAR;                                                                        \
} while (0)

template<int BMT, bool BIAS, bool RELU>
__global__ void __launch_bounds__(512, 2) gemm8p(
    const short* __restrict__ A, int lda,
    const short* __restrict__ Bm, int ldb,
    short* __restrict__ C, int ldc,
    const float* __restrict__ bias, int K) {
  constexpr int BM = BMT * 128;
  constexpr int MT = BMT * 4;            // M-frags per wave
  constexpr int MH = MT / 2;             // M-frags per quadrant
  constexpr int AH = (BM / 2) * 64;      // shorts per A-half slot
  constexpr int BUF = BM * 64 + 16384;   // shorts per buffer (A + B)
  constexpr int VGATE = BMT + 2;         // p2's stage loads (A unit: BMT, B unit: 2)

  __shared__ __align__(16) short lds[2 * BUF];

  const int tid = threadIdx.x;
  const int lane = tid & 63;
  const int wave = tid >> 6;
  const int wm = wave >> 2, wn = wave & 3;
  const int l15 = lane & 15, l4 = lane >> 4;

  // T1: XCD-aware bijective swizzle (grid size is a multiple of 8)
  const int id = blockIdx.y * gridDim.x + blockIdx.x;
  const int per = (gridDim.x * gridDim.y) >> 3;
  const int swz = (id & 7) * per + (id >> 3);
  const int bn = swz % gridDim.x;
  const int bm = swz / gridDim.x;

  const short* Ab = A + (long)bm * BM * lda;
  const short* Bb = Bm + (long)bn * 256 * ldb;
  const int NTILE = K >> 6;

  auto stA = [&](int t, int h, int par) {
    short* dst = lds + par * BUF + h * AH;
    const int k0 = t << 6;
#pragma unroll
    for (int l = 0; l < BMT; l++) {
      int c = l * 512 + tid;
      int r = c >> 3;
      int cg = (c & 7) ^ (r & 7);
      gload_lds16(Ab + (long)(h * (BM / 2) + r) * lda + k0 + cg * 8, dst + c * 8);
    }
  };
  auto stB = [&](int t, int h, int par) {
    short* dst = lds + par * BUF + BM * 64 + h * 8192;
    const int k0 = t << 6;
#pragma unroll
    for (int l = 0; l < 2; l++) {
      int c = l * 512 + tid;
      int r = c >> 3;
      int cg = (c & 7) ^ (r & 7);
      gload_lds16(Bb + (long)(h * 128 + r) * ldb + k0 + cg * 8, dst + c * 8);
    }
  };

  f32x4 acc[MT][4];
#pragma unroll
  for (int i = 0; i < MT; i++)
#pragma unroll
    for (int j = 0; j < 4; j++) acc[i][j] = (f32x4){0.f, 0.f, 0.f, 0.f};

  bf16x8 aF[2][MH][2];   // [mh][m2][ks] — mh0 doubles as next-tile bank
  bf16x8 bF[2][2][2];    // [nh][n2][ks] — single generation

  // prologue: stage tiles 0 (par 0) and 1 (par 1); gate; read A-mh0(t0)
  stA(0, 0, 0); stA(0, 1, 0); stB(0, 0, 0); stB(0, 1, 0);
  stA(1, 0, 1); stA(1, 1, 1); stB(1, 0, 1); stB(1, 1, 1);
  SB0;
  asm volatile("s_waitcnt vmcnt(%0)" :: "i"(2 * BMT + 4) : "memory");  // allow t1
  BAR; SB0;
  RD_A(0, 0);

  for (int g = 0; g < NTILE; g += 2) {
    ITERG(g, 0);
    ITERG(g + 1, 1);
  }

  // epilogue: C/D layout col=lane&15, row=(lane>>4)*4+r
  const int col0 = bn * 256 + wn * 64;
  const int row0 = bm * BM + wm * (BM / 2);
#pragma unroll
  for (int nt = 0; nt < 4; nt++) {
    const int col = col0 + nt * 16 + l15;
    const float bb = BIAS ? bias[col] : 0.f;
#pragma unroll
    for (int mt = 0; mt < MT; mt++) {
      const int rbase = row0 + mt * 16 + l4 * 4;
#pragma unroll
      for (int r = 0; r < 4; r++) {
        float v = acc[mt][nt][r] + bb;
        if (RELU) v = v > 0.f ? v : 0.f;
        C[(long)(rbase + r) * ldc + col] = f2bf(v);
      }
    }
  }
}

// ---------------- simple m97-style GEMM (kept for qk & scores) ----------------
template<bool OUTF32>
__global__ void __launch_bounds__(256) gemm_bt(
    const short* __restrict__ A, int lda, long strideA,
    const short* __restrict__ Bm, int ldb, long strideB,
    void* __restrict__ Cv, int ldc, long strideC, int K) {
  const int bn = blockIdx.x;
  const int bm = blockIdx.y;
  const int bz = blockIdx.z;
  const short* Ab = A + (long)bz * strideA + (long)bm * 128 * lda;
  const short* Bb = Bm + (long)bz * strideB + (long)bn * 128 * ldb;

  __shared__ short lA[128 * 64];
  __shared__ short lB[128 * 64];

  const int tid = threadIdx.x;
  const int lane = tid & 63;
  const int wave = tid >> 6;
  const int wr = wave >> 1, wc = wave & 1;

  f32x4 acc[4][4];
#pragma unroll
  for (int i = 0; i < 4; i++)
#pragma unroll
    for (int j = 0; j < 4; j++) acc[i][j] = (f32x4){0.f, 0.f, 0.f, 0.f};

  for (int k0 = 0; k0 < K; k0 += 64) {
    __syncthreads();
#pragma unroll
    for (int i = 0; i < 4; i++) {
      int c = i * 256 + tid;
      int row = c >> 3;
      int col = (c & 7) * 8;
      gload_lds16(Ab + (long)row * lda + k0 + col, &lA[c * 8]);
      gload_lds16(Bb + (long)row * ldb + k0 + col, &lB[c * 8]);
    }
    __syncthreads();

#pragma unroll
    for (int ks = 0; ks < 2; ks++) {
      bf16x8 af[4], bfr[4];
#pragma unroll
      for (int t = 0; t < 4; t++) {
        af[t]  = *(const bf16x8*)&lA[(wr * 64 + t * 16 + (lane & 15)) * 64 + ks * 32 + (lane >> 4) * 8];
        bfr[t] = *(const bf16x8*)&lB[(wc * 64 + t * 16 + (lane & 15)) * 64 + ks * 32 + (lane >> 4) * 8];
      }
#pragma unroll
      for (int mt = 0; mt < 4; mt++)
#pragma unroll
        for (int nt = 0; nt < 4; nt++)
          acc[mt][nt] = __builtin_amdgcn_mfma_f32_16x16x32_bf16(af[mt], bfr[nt], acc[mt][nt], 0, 0, 0);
    }
  }

  const int col0 = bn * 128 + wc * 64;
  const int row0 = bm * 128 + wr * 64;
#pragma unroll
  for (int mt = 0; mt < 4; mt++) {
#pragma unroll
    for (int nt = 0; nt < 4; nt++) {
      int col = col0 + nt * 16 + (lane & 15);
      int rbase = row0 + mt * 16 + (lane >> 4) * 4;
#pragma unroll
      for (int r = 0; r < 4; r++) {
        float v = acc[mt][nt][r];
        long off = (long)bz * strideC + (long)(rbase + r) * ldc + col;
        if (OUTF32) ((float*)Cv)[off] = v;
        else        ((short*)Cv)[off] = f2bf(v);
      }
    }
  }
}

// ---------------- reductions ----------------
__device__ __forceinline__ float wave_sum(float v) {
#pragma unroll
  for (int o = 32; o > 0; o >>= 1) v += __shfl_xor(v, o, 64);
  return v;
}
__device__ __forceinline__ float wave_max(float v) {
#pragma unroll
  for (int o = 32; o > 0; o >>= 1) v = fmaxf(v, __shfl_xor(v, o, 64));
  return v;
}

// ---------------- in-place row softmax over 2048 cols, then /H ----------------
__global__ void __launch_bounds__(256) softmax_div16(float* __restrict__ s) {
  const int tid = threadIdx.x;
  float* p = s + (long)blockIdx.x * 2048;
  float4 a = *(const float4*)(p + tid * 8);
  float4 b = *(const float4*)(p + tid * 8 + 4);
  float m = fmaxf(fmaxf(fmaxf(a.x, a.y), fmaxf(a.z, a.w)),
                  fmaxf(fmaxf(b.x, b.y), fmaxf(b.z, b.w)));
  __shared__ float red[4];
  m = wave_max(m);
  if ((tid & 63) == 0) red[tid >> 6] = m;
  __syncthreads();
  m = fmaxf(fmaxf(red[0], red[1]), fmaxf(red[2], red[3]));

  float e0 = __expf(a.x - m), e1 = __expf(a.y - m), e2 = __expf(a.z - m), e3 = __expf(a.w - m);
  float e4 = __expf(b.x - m), e5 = __expf(b.y - m), e6 = __expf(b.z - m), e7 = __expf(b.w - m);
  float sum = (e0 + e1) + (e2 + e3) + ((e4 + e5) + (e6 + e7));
  __syncthreads();
  sum = wave_sum(sum);
  if ((tid & 63) == 0) red[tid >> 6] = sum;
  __syncthreads();
  sum = red[0] + red[1] + red[2] + red[3];
  float inv = 1.0f / (sum * 16.0f);
  a.x = e0 * inv; a.y = e1 * inv; a.z = e2 * inv; a.w = e3 * inv;
  b.x = e4 * inv; b.y = e5 * inv; b.z = e6 * inv; b.w = e7 * inv;
  *(float4*)(p + tid * 8) = a;
  *(float4*)(p + tid * 8 + 4) = b;
}

// ---------------- fused residual + LayerNorm (f32 out) ----------------
__global__ void __launch_bounds__(256) ln_fuse(
    const short* __restrict__ ctx, const short* __restrict__ ffn,
    const float* __restrict__ g, const float* __restrict__ bta,
    float* __restrict__ out) {
  const int tid = threadIdx.x;
  long base = (long)blockIdx.x * 1024 + tid * 4;
  short4 c4 = *(const short4*)(ctx + base);
  short4 f4 = *(const short4*)(ffn + base);
  float x0 = bf2f(c4.x) + bf2f(f4.x);
  float x1 = bf2f(c4.y) + bf2f(f4.y);
  float x2 = bf2f(c4.z) + bf2f(f4.z);
  float x3 = bf2f(c4.w) + bf2f(f4.w);

  float s = (x0 + x1) + (x2 + x3);
  float q = (x0 * x0 + x1 * x1) + (x2 * x2 + x3 * x3);
  __shared__ float rs[4], rq[4];
  s = wave_sum(s);
  q = wave_sum(q);
  if ((tid & 63) == 0) { rs[tid >> 6] = s; rq[tid >> 6] = q; }
  __syncthreads();
  float S = rs[0] + rs[1] + rs[2] + rs[3];
  float Q = rq[0] + rq[1] + rq[2] + rq[3];
  float mu = S * (1.0f / 1024.0f);
  float var = Q * (1.0f / 1024.0f) - mu * mu;
  float inv = rsqrtf(var + 1e-5f);

  float4 g4 = *(const float4*)(g + tid * 4);
  float4 b4 = *(const float4*)(bta + tid * 4);
  float4 o;
  o.x = (x0 - mu) * inv * g4.x + b4.x;
  o.y = (x1 - mu) * inv * g4.y + b4.y;
  o.z = (x2 - mu) * inv * g4.z + b4.z;
  o.w = (x3 - mu) * inv * g4.w + b4.w;
  *(float4*)(out + base) = o;
}

// ---------------- launch ----------------
extern "C" void kernel_launch(void* const* d_in, const int* in_sizes, int n_in,
                              void* d_out, int out_size, void* d_ws, size_t ws_size,
                              hipStream_t stream) {
  const float* inputs = (const float*)d_in[0];
  const float* Wq = (const float*)d_in[1];
  const float* Wk = (const float*)d_in[2];
  const float* Wv = (const float*)d_in[3];
  const float* Wo = (const float*)d_in[4];
  const float* W1 = (const float*)d_in[5];
  const float* b1 = (const float*)d_in[6];
  const float* W2 = (const float*)d_in[7];
  const float* b2 = (const float*)d_in[8];
  const float* ln_g = (const float*)d_in[9];
  const float* ln_b = (const float*)d_in[10];

  char* w = (char*)d_ws;
  short* in_bf = (short*)w;  w += (long)MTOK * D_ * 2;
  short* wqk   = (short*)w;  w += 128L * D_ * 2;
  short* wv    = (short*)w;  w += (long)D_ * D_ * 2;
  short* wo    = (short*)w;  w += (long)D_ * D_ * 2;
  short* w1    = (short*)w;  w += (long)F_ * D_ * 2;
  short* w2    = (short*)w;  w += (long)D_ * F_ * 2;
  short* qkh   = (short*)w;  w += (long)MTOK * 128 * 2;
  short* vbf   = (short*)w;  w += (long)MTOK * D_ * 2;
  short* ctxbf = (short*)w;  w += (long)MTOK * D_ * 2;
  short* hbf   = (short*)w;  w += (long)MTOK * F_ * 2;
  short* ffnbf = (short*)w;  w += (long)MTOK * D_ * 2;

  float* out  = (float*)d_out;                 // [8192][1024]
  float* attn = out + (long)MTOK * D_;         // [4][2048][2048]

  const float scale = 0.125f;  // DH^-0.5

  convert_bf16<<<dim3((MTOK * D_) >> 10), 256, 0, stream>>>(inputs, in_bf, (long)MTOK * D_, 1.0f);
  convert_bf16<<<dim3((64 * D_) >> 10), 256, 0, stream>>>(Wq + 960 * D_, wqk, 64L * D_, scale);
  convert_bf16<<<dim3((64 * D_) >> 10), 256, 0, stream>>>(Wk + 960 * D_, wqk + 64L * D_, 64L * D_, 1.0f);
  convert_bf16<<<dim3((D_ * D_) >> 10), 256, 0, stream>>>(Wv, wv, (long)D_ * D_, 1.0f);
  convert_bf16<<<dim3((D_ * D_) >> 10), 256, 0, stream>>>(Wo, wo, (long)D_ * D_, 1.0f);
  convert_bf16<<<dim3((F_ * D_) >> 10), 256, 0, stream>>>(W1, w1, (long)F_ * D_, 1.0f);
  convert_bf16<<<dim3((F_ * D_) >> 10), 256, 0, stream>>>(W2, w2, (long)F_ * D_, 1.0f);

  // qH|kH = inputs @ wqk^T   (M=8192, N=128, K=1024) — small, m97 kernel
  gemm_bt<false><<<dim3(1, 64, 1), 256, 0, stream>>>(
      in_bf, D_, 0, wqk, D_, 0, qkh, 128, 0, D_);
  // v = inputs @ Wv^T        (M=8192, N=1024, K=1024) — pipelined, 128x256
  gemm8p<1, false, false><<<dim3(4, 64), 512, 0, stream>>>(
      in_bf, D_, wv, D_, vbf, D_, nullptr, D_);
  // scores[b] = qH @ kH^T    (M=2048, N=2048, K=64, batch=4) -> attn (f32)
  gemm_bt<true><<<dim3(16, 16, 4), 256, 0, stream>>>(
      qkh, 128, (long)L_ * 128, qkh + 64, 128, (long)L_ * 128,
      attn, L_, (long)L_ * L_, 64);
  // softmax rows (in place) + /H
  softmax_div16<<<dim3(MTOK), 256, 0, stream>>>(attn);
  // context = v @ Wo^T       (M=8192, N=1024, K=1024) — pipelined, 128x256
  gemm8p<1, false, false><<<dim3(4, 64), 512, 0, stream>>>(
      vbf, D_, wo, D_, ctxbf, D_, nullptr, D_);
  // h = relu(ctx @ W1^T + b1) (M=8192, N=4096, K=1024) — pipelined, 256x256
  gemm8p<2, true, true><<<dim3(16, 32), 512, 0, stream>>>(
      ctxbf, D_, w1, D_, hbf, F_, b1, D_);
  // ffn = h @ W2^T + b2       (M=8192, N=1024, K=4096) — pipelined, 128x256
  gemm8p<1, true, false><<<dim3(4, 64), 512, 0, stream>>>(
      hbf, F_, w2, F_, ffnbf, D_, b2, F_);
  // out = LN(ctx + ffn)
  ln_fuse<<<dim3(MTOK), 256, 0, stream>>>(ctxbf, ffnbf, ln_g, ln_b, out);
}

// Round 4
// 297.893 us; speedup vs baseline: 1.1302x; 1.1302x over previous
//
#include <hip/hip_runtime.h>
#include <hip/hip_bf16.h>
#include <stdint.h>

// Problem constants
#define D_ 1024
#define H_ 16
#define DH_ 64
#define F_ 4096
#define B_ 4
#define L_ 2048
#define MTOK 8192   // B_*L_

typedef __attribute__((ext_vector_type(8))) short bf16x8;
typedef __attribute__((ext_vector_type(4))) float f32x4;

__device__ __forceinline__ short f2bf(float f) {
  uint32_t u = __float_as_uint(f);
  uint32_t r = (u + 0x7FFFu + ((u >> 16) & 1u)) >> 16;
  return (short)(uint16_t)r;
}
__device__ __forceinline__ float bf2f(short s) {
  return __uint_as_float(((uint32_t)(uint16_t)s) << 16);
}

__device__ __forceinline__ void gload_lds16(const short* g, short* l) {
  __builtin_amdgcn_global_load_lds(
      (const __attribute__((address_space(1))) void*)g,
      (__attribute__((address_space(3))) void*)l,
      16, 0, 0);
}

// ---------------- f32 -> bf16 conversion (with optional scale) ----------------
__global__ void __launch_bounds__(256) convert_bf16(
    const float* __restrict__ src, short* __restrict__ dst, long n, float scale) {
  long i = ((long)blockIdx.x * 256 + threadIdx.x) * 4;
  long stride = (long)gridDim.x * 1024;
  for (; i < n; i += stride) {
    float4 f = *(const float4*)(src + i);
    short4 o;
    o.x = f2bf(f.x * scale);
    o.y = f2bf(f.y * scale);
    o.z = f2bf(f.z * scale);
    o.w = f2bf(f.w * scale);
    *(short4*)(dst + i) = o;
  }
}

// =====================================================================
// m201-style 8-phase GEMM: C[M,N] = A[M,K] @ B[N,K]^T (+bias, relu)
// BN=256, BM=BMT*128, BK=64, 8 waves (2M x 4N), per-wave (BMT*64) x 64.
// Phases P0..P3 = C-quadrants (0,0),(0,1),(1,0),(1,1) per K-tile.
// Reads: P0 = A-h0 + B-h0 (early lgkm), P1 = B-h1, P2 = A-h1, P3 = none.
// Stages: P0 -> A1(g+1) [other buf], P2 -> B0(g+2), P3 -> B1+A0(g+2).
// Gate: counted vmcnt AFTER Q(1,1) at P3, once per K-tile; vmcnt(0) only
// at tile NTILE-2; no sched_barrier pinning; raw s_barrier 2x per phase.
// T2 swizzle: linear LDS dest, pre-swizzled global source, swizzled read.
// T1 XCD swizzle on flat block id (grid size must be multiple of 8).
// =====================================================================
#define BAR   __builtin_amdgcn_s_barrier()
#define PRIO1 __builtin_amdgcn_s_setprio(1)
#define PRIO0 __builtin_amdgcn_s_setprio(0)
#define LGKM0 asm volatile("s_waitcnt lgkmcnt(0)" ::: "memory")

#define RD_A(mh_, par_) do {                                                  \
  const short* bp = lds + (par_) * BUF + wm * ASLOT;                          \
  _Pragma("unroll")                                                           \
  for (int m2 = 0; m2 < MH; m2++) {                                           \
    const int r = ((mh_) * MH + m2) * 16 + l15;                               \
    _Pragma("unroll")                                                         \
    for (int ks = 0; ks < 2; ks++)                                            \
      aF[mh_][m2][ks] =                                                       \
          *(const bf16x8*)(bp + r * 64 + (((ks * 4 + l4) ^ (r & 7)) << 3));   \
  } } while (0)

#define RD_B(nh_, par_) do {                                                  \
  const short* bp = lds + (par_) * BUF + BM * 64 + (wn >> 1) * 8192;          \
  _Pragma("unroll")                                                           \
  for (int n2 = 0; n2 < 2; n2++) {                                            \
    const int r = (wn & 1) * 64 + ((nh_) * 2 + n2) * 16 + l15;                \
    _Pragma("unroll")                                                         \
    for (int ks = 0; ks < 2; ks++)                                            \
      bF[nh_][n2][ks] =                                                       \
          *(const bf16x8*)(bp + r * 64 + (((ks * 4 + l4) ^ (r & 7)) << 3));   \
  } } while (0)

#define QUAD(mh_, nh_) do {                                                   \
  _Pragma("unroll")                                                           \
  for (int ks = 0; ks < 2; ks++)                                              \
    _Pragma("unroll")                                                         \
    for (int m2 = 0; m2 < MH; m2++)                                           \
      _Pragma("unroll")                                                       \
      for (int n2 = 0; n2 < 2; n2++)                                          \
        acc[(mh_) * MH + m2][(nh_) * 2 + n2] =                                \
            __builtin_amdgcn_mfma_f32_16x16x32_bf16(                          \
                aF[mh_][m2][ks], bF[nh_][n2][ks],                             \
                acc[(mh_) * MH + m2][(nh_) * 2 + n2], 0, 0, 0);               \
} while (0)

// SN: stage A1(g+1); SPP: stage B0/B1/A0(g+2); GK: 1=vmcnt(VG), 2=vmcnt(0), 0=none
#define ITER(g_, SN, SPP, GK) do {                                            \
  const int par = (g_) & 1;                                                   \
  /* P0 */                                                                    \
  RD_A(0, par); RD_B(0, par);                                                 \
  if (SN) stA((g_) + 1, 1, par ^ 1);                                          \
  if (BMT == 2) asm volatile("s_waitcnt lgkmcnt(8)" ::: "memory");            \
  BAR; LGKM0;                                                                 \
  PRIO1; QUAD(0, 0); PRIO0;                                                   \
  BAR;                                                                        \
  /* P1 */                                                                    \
  RD_B(1, par);                                                               \
  BAR; LGKM0;                                                                 \
  PRIO1; QUAD(0, 1); PRIO0;                                                   \
  BAR;                                                                        \
  /* P2 */                                                                    \
  RD_A(1, par);                                                               \
  if (SPP) stB((g_) + 2, 0, par);                                             \
  BAR; LGKM0;                                                                 \
  PRIO1; QUAD(1, 0); PRIO0;                                                   \
  BAR;                                                                        \
  /* P3 */                                                                    \
  if (SPP) { stB((g_) + 2, 1, par); stA((g_) + 2, 0, par); }                  \
  PRIO1; QUAD(1, 1); PRIO0;                                                   \
  if (GK == 1) asm volatile("s_waitcnt vmcnt(%0)" :: "i"(VG) : "memory");     \
  else if (GK == 2) asm volatile("s_waitcnt vmcnt(0)" ::: "memory");          \
  BAR;                                                                        \
} while (0)

template<int BMT, bool BIAS, bool RELU>
__global__ void __launch_bounds__(512, 2) gemm8p(
    const short* __restrict__ A, int lda,
    const short* __restrict__ Bm, int ldb,
    short* __restrict__ C, int ldc,
    const float* __restrict__ bias, int K) {
  constexpr int BM = BMT * 128;
  constexpr int MT = BMT * 4;            // M-frags per wave
  constexpr int MH = MT / 2;             // M-frags per quadrant
  constexpr int LA = BMT;                // per-thread loads per A-half
  constexpr int LB = 2;                  // per-thread loads per B-half
  constexpr int ASLOT = (BM / 2) * 64;   // shorts per A-half slot
  constexpr int BUF = BM * 64 + 16384;   // shorts per buffer (A + B)
  constexpr int VG = 2 * LB + LA;        // steady-state outstanding loads

  __shared__ __align__(16) short lds[2 * BUF];

  const int tid = threadIdx.x;
  const int lane = tid & 63;
  const int wave = tid >> 6;
  const int wm = wave >> 2, wn = wave & 3;
  const int l15 = lane & 15, l4 = lane >> 4;

  // T1: XCD-aware bijective swizzle (grid size is a multiple of 8)
  const int id = blockIdx.y * gridDim.x + blockIdx.x;
  const int per = (gridDim.x * gridDim.y) >> 3;
  const int swz = (id & 7) * per + (id >> 3);
  const int bn = swz % gridDim.x;
  const int bm = swz / gridDim.x;

  const short* Ab = A + (long)bm * BM * lda;
  const short* Bb = Bm + (long)bn * 256 * ldb;
  const int NTILE = K >> 6;

  auto stA = [&](int t, int h, int par) {
    short* dst = lds + par * BUF + h * ASLOT;
    const int k0 = t << 6;
#pragma unroll
    for (int l = 0; l < LA; l++) {
      int c = l * 512 + tid;
      int r = c >> 3;
      int cg = (c & 7) ^ (r & 7);
      gload_lds16(Ab + (long)(h * (BM / 2) + r) * lda + k0 + cg * 8, dst + c * 8);
    }
  };
  auto stB = [&](int t, int h, int par) {
    short* dst = lds + par * BUF + BM * 64 + h * 8192;
    const int k0 = t << 6;
#pragma unroll
    for (int l = 0; l < LB; l++) {
      int c = l * 512 + tid;
      int r = c >> 3;
      int cg = (c & 7) ^ (r & 7);
      gload_lds16(Bb + (long)(h * 128 + r) * ldb + k0 + cg * 8, dst + c * 8);
    }
  };

  f32x4 acc[MT][4];
#pragma unroll
  for (int i = 0; i < MT; i++)
#pragma unroll
    for (int j = 0; j < 4; j++) acc[i][j] = (f32x4){0.f, 0.f, 0.f, 0.f};

  bf16x8 aF[2][MH][2];   // [mh][m2][ks]
  bf16x8 bF[2][2][2];    // [nh][n2][ks] — retained P0->P2 / P1->P3

  // prologue: tile0 fully; tile1 all but A1 (A1(t1) staged at tile0 P0)
  stA(0, 0, 0); stA(0, 1, 0); stB(0, 0, 0); stB(0, 1, 0);
  stB(1, 0, 1); stB(1, 1, 1); stA(1, 0, 1);
  asm volatile("s_waitcnt vmcnt(%0)" :: "i"(VG) : "memory");  // tile0 landed
  BAR;

  for (int g = 0; g < NTILE - 2; ++g) ITER(g, 1, 1, 1);
  ITER(NTILE - 2, 1, 0, 2);
  ITER(NTILE - 1, 0, 0, 0);

  // epilogue: C/D layout col=lane&15, row=(lane>>4)*4+r
  const int col0 = bn * 256 + wn * 64;
  const int row0 = bm * BM + wm * (BM / 2);
#pragma unroll
  for (int nt = 0; nt < 4; nt++) {
    const int col = col0 + nt * 16 + l15;
    const float bb = BIAS ? bias[col] : 0.f;
#pragma unroll
    for (int mt = 0; mt < MT; mt++) {
      const int rbase = row0 + mt * 16 + l4 * 4;
#pragma unroll
      for (int r = 0; r < 4; r++) {
        float v = acc[mt][nt][r] + bb;
        if (RELU) v = v > 0.f ? v : 0.f;
        C[(long)(rbase + r) * ldc + col] = f2bf(v);
      }
    }
  }
}

// ---------------- simple m97-style GEMM (kept for qk & scores) ----------------
template<bool OUTF32>
__global__ void __launch_bounds__(256) gemm_bt(
    const short* __restrict__ A, int lda, long strideA,
    const short* __restrict__ Bm, int ldb, long strideB,
    void* __restrict__ Cv, int ldc, long strideC, int K) {
  const int bn = blockIdx.x;
  const int bm = blockIdx.y;
  const int bz = blockIdx.z;
  const short* Ab = A + (long)bz * strideA + (long)bm * 128 * lda;
  const short* Bb = Bm + (long)bz * strideB + (long)bn * 128 * ldb;

  __shared__ short lA[128 * 64];
  __shared__ short lB[128 * 64];

  const int tid = threadIdx.x;
  const int lane = tid & 63;
  const int wave = tid >> 6;
  const int wr = wave >> 1, wc = wave & 1;

  f32x4 acc[4][4];
#pragma unroll
  for (int i = 0; i < 4; i++)
#pragma unroll
    for (int j = 0; j < 4; j++) acc[i][j] = (f32x4){0.f, 0.f, 0.f, 0.f};

  for (int k0 = 0; k0 < K; k0 += 64) {
    __syncthreads();
#pragma unroll
    for (int i = 0; i < 4; i++) {
      int c = i * 256 + tid;
      int row = c >> 3;
      int col = (c & 7) * 8;
      gload_lds16(Ab + (long)row * lda + k0 + col, &lA[c * 8]);
      gload_lds16(Bb + (long)row * ldb + k0 + col, &lB[c * 8]);
    }
    __syncthreads();

#pragma unroll
    for (int ks = 0; ks < 2; ks++) {
      bf16x8 af[4], bfr[4];
#pragma unroll
      for (int t = 0; t < 4; t++) {
        af[t]  = *(const bf16x8*)&lA[(wr * 64 + t * 16 + (lane & 15)) * 64 + ks * 32 + (lane >> 4) * 8];
        bfr[t] = *(const bf16x8*)&lB[(wc * 64 + t * 16 + (lane & 15)) * 64 + ks * 32 + (lane >> 4) * 8];
      }
#pragma unroll
      for (int mt = 0; mt < 4; mt++)
#pragma unroll
        for (int nt = 0; nt < 4; nt++)
          acc[mt][nt] = __builtin_amdgcn_mfma_f32_16x16x32_bf16(af[mt], bfr[nt], acc[mt][nt], 0, 0, 0);
    }
  }

  const int col0 = bn * 128 + wc * 64;
  const int row0 = bm * 128 + wr * 64;
#pragma unroll
  for (int mt = 0; mt < 4; mt++) {
#pragma unroll
    for (int nt = 0; nt < 4; nt++) {
      int col = col0 + nt * 16 + (lane & 15);
      int rbase = row0 + mt * 16 + (lane >> 4) * 4;
#pragma unroll
      for (int r = 0; r < 4; r++) {
        float v = acc[mt][nt][r];
        long off = (long)bz * strideC + (long)(rbase + r) * ldc + col;
        if (OUTF32) ((float*)Cv)[off] = v;
        else        ((short*)Cv)[off] = f2bf(v);
      }
    }
  }
}

// ---------------- reductions ----------------
__device__ __forceinline__ float wave_sum(float v) {
#pragma unroll
  for (int o = 32; o > 0; o >>= 1) v += __shfl_xor(v, o, 64);
  return v;
}
__device__ __forceinline__ float wave_max(float v) {
#pragma unroll
  for (int o = 32; o > 0; o >>= 1) v = fmaxf(v, __shfl_xor(v, o, 64));
  return v;
}

// ---------------- in-place row softmax over 2048 cols, then /H ----------------
__global__ void __launch_bounds__(256) softmax_div16(float* __restrict__ s) {
  const int tid = threadIdx.x;
  float* p = s + (long)blockIdx.x * 2048;
  float4 a = *(const float4*)(p + tid * 8);
  float4 b = *(const float4*)(p + tid * 8 + 4);
  float m = fmaxf(fmaxf(fmaxf(a.x, a.y), fmaxf(a.z, a.w)),
                  fmaxf(fmaxf(b.x, b.y), fmaxf(b.z, b.w)));
  __shared__ float red[4];
  m = wave_max(m);
  if ((tid & 63) == 0) red[tid >> 6] = m;
  __syncthreads();
  m = fmaxf(fmaxf(red[0], red[1]), fmaxf(red[2], red[3]));

  float e0 = __expf(a.x - m), e1 = __expf(a.y - m), e2 = __expf(a.z - m), e3 = __expf(a.w - m);
  float e4 = __expf(b.x - m), e5 = __expf(b.y - m), e6 = __expf(b.z - m), e7 = __expf(b.w - m);
  float sum = (e0 + e1) + (e2 + e3) + ((e4 + e5) + (e6 + e7));
  __syncthreads();
  sum = wave_sum(sum);
  if ((tid & 63) == 0) red[tid >> 6] = sum;
  __syncthreads();
  sum = red[0] + red[1] + red[2] + red[3];
  float inv = 1.0f / (sum * 16.0f);
  a.x = e0 * inv; a.y = e1 * inv; a.z = e2 * inv; a.w = e3 * inv;
  b.x = e4 * inv; b.y = e5 * inv; b.z = e6 * inv; b.w = e7 * inv;
  *(float4*)(p + tid * 8) = a;
  *(float4*)(p + tid * 8 + 4) = b;
}

// ---------------- fused residual + LayerNorm (f32 out) ----------------
__global__ void __launch_bounds__(256) ln_fuse(
    const short* __restrict__ ctx, const short* __restrict__ ffn,
    const float* __restrict__ g, const float* __restrict__ bta,
    float* __restrict__ out) {
  const int tid = threadIdx.x;
  long base = (long)blockIdx.x * 1024 + tid * 4;
  short4 c4 = *(const short4*)(ctx + base);
  short4 f4 = *(const short4*)(ffn + base);
  float x0 = bf2f(c4.x) + bf2f(f4.x);
  float x1 = bf2f(c4.y) + bf2f(f4.y);
  float x2 = bf2f(c4.z) + bf2f(f4.z);
  float x3 = bf2f(c4.w) + bf2f(f4.w);

  float s = (x0 + x1) + (x2 + x3);
  float q = (x0 * x0 + x1 * x1) + (x2 * x2 + x3 * x3);
  __shared__ float rs[4], rq[4];
  s = wave_sum(s);
  q = wave_sum(q);
  if ((tid & 63) == 0) { rs[tid >> 6] = s; rq[tid >> 6] = q; }
  __syncthreads();
  float S = rs[0] + rs[1] + rs[2] + rs[3];
  float Q = rq[0] + rq[1] + rq[2] + rq[3];
  float mu = S * (1.0f / 1024.0f);
  float var = Q * (1.0f / 1024.0f) - mu * mu;
  float inv = rsqrtf(var + 1e-5f);

  float4 g4 = *(const float4*)(g + tid * 4);
  float4 b4 = *(const float4*)(bta + tid * 4);
  float4 o;
  o.x = (x0 - mu) * inv * g4.x + b4.x;
  o.y = (x1 - mu) * inv * g4.y + b4.y;
  o.z = (x2 - mu) * inv * g4.z + b4.z;
  o.w = (x3 - mu) * inv * g4.w + b4.w;
  *(float4*)(out + base) = o;
}

// ---------------- launch ----------------
extern "C" void kernel_launch(void* const* d_in, const int* in_sizes, int n_in,
                              void* d_out, int out_size, void* d_ws, size_t ws_size,
                              hipStream_t stream) {
  const float* inputs = (const float*)d_in[0];
  const float* Wq = (const float*)d_in[1];
  const float* Wk = (const float*)d_in[2];
  const float* Wv = (const float*)d_in[3];
  const float* Wo = (const float*)d_in[4];
  const float* W1 = (const float*)d_in[5];
  const float* b1 = (const float*)d_in[6];
  const float* W2 = (const float*)d_in[7];
  const float* b2 = (const float*)d_in[8];
  const float* ln_g = (const float*)d_in[9];
  const float* ln_b = (const float*)d_in[10];

  char* w = (char*)d_ws;
  short* in_bf = (short*)w;  w += (long)MTOK * D_ * 2;
  short* wqk   = (short*)w;  w += 128L * D_ * 2;
  short* wv    = (short*)w;  w += (long)D_ * D_ * 2;
  short* wo    = (short*)w;  w += (long)D_ * D_ * 2;
  short* w1    = (short*)w;  w += (long)F_ * D_ * 2;
  short* w2    = (short*)w;  w += (long)D_ * F_ * 2;
  short* qkh   = (short*)w;  w += (long)MTOK * 128 * 2;
  short* vbf   = (short*)w;  w += (long)MTOK * D_ * 2;
  short* ctxbf = (short*)w;  w += (long)MTOK * D_ * 2;
  short* hbf   = (short*)w;  w += (long)MTOK * F_ * 2;
  short* ffnbf = (short*)w;  w += (long)MTOK * D_ * 2;

  float* out  = (float*)d_out;                 // [8192][1024]
  float* attn = out + (long)MTOK * D_;         // [4][2048][2048]

  const float scale = 0.125f;  // DH^-0.5

  convert_bf16<<<dim3((MTOK * D_) >> 10), 256, 0, stream>>>(inputs, in_bf, (long)MTOK * D_, 1.0f);
  convert_bf16<<<dim3((64 * D_) >> 10), 256, 0, stream>>>(Wq + 960 * D_, wqk, 64L * D_, scale);
  convert_bf16<<<dim3((64 * D_) >> 10), 256, 0, stream>>>(Wk + 960 * D_, wqk + 64L * D_, 64L * D_, 1.0f);
  convert_bf16<<<dim3((D_ * D_) >> 10), 256, 0, stream>>>(Wv, wv, (long)D_ * D_, 1.0f);
  convert_bf16<<<dim3((D_ * D_) >> 10), 256, 0, stream>>>(Wo, wo, (long)D_ * D_, 1.0f);
  convert_bf16<<<dim3((F_ * D_) >> 10), 256, 0, stream>>>(W1, w1, (long)F_ * D_, 1.0f);
  convert_bf16<<<dim3((F_ * D_) >> 10), 256, 0, stream>>>(W2, w2, (long)F_ * D_, 1.0f);

  // qH|kH = inputs @ wqk^T   (M=8192, N=128, K=1024) — small, m97 kernel
  gemm_bt<false><<<dim3(1, 64, 1), 256, 0, stream>>>(
      in_bf, D_, 0, wqk, D_, 0, qkh, 128, 0, D_);
  // v = inputs @ Wv^T        (M=8192, N=1024, K=1024) — 8-phase, 128x256
  gemm8p<1, false, false><<<dim3(4, 64), 512, 0, stream>>>(
      in_bf, D_, wv, D_, vbf, D_, nullptr, D_);
  // scores[b] = qH @ kH^T    (M=2048, N=2048, K=64, batch=4) -> attn (f32)
  gemm_bt<true><<<dim3(16, 16, 4), 256, 0, stream>>>(
      qkh, 128, (long)L_ * 128, qkh + 64, 128, (long)L_ * 128,
      attn, L_, (long)L_ * L_, 64);
  // softmax rows (in place) + /H
  softmax_div16<<<dim3(MTOK), 256, 0, stream>>>(attn);
  // context = v @ Wo^T       (M=8192, N=1024, K=1024) — 8-phase, 128x256
  gemm8p<1, false, false><<<dim3(4, 64), 512, 0, stream>>>(
      vbf, D_, wo, D_, ctxbf, D_, nullptr, D_);
  // h = relu(ctx @ W1^T + b1) (M=8192, N=4096, K=1024) — 8-phase, 256x256
  gemm8p<2, true, true><<<dim3(16, 32), 512, 0, stream>>>(
      ctxbf, D_, w1, D_, hbf, F_, b1, D_);
  // ffn = h @ W2^T + b2       (M=8192, N=1024, K=4096) — 8-phase, 128x256
  gemm8p<1, true, false><<<dim3(4, 64), 512, 0, stream>>>(
      hbf, F_, w2, F_, ffnbf, D_, b2, F_);
  // out = LN(ctx + ffn)
  ln_fuse<<<dim3(MTOK), 256, 0, stream>>>(ctxbf, ffnbf, ln_g, ln_b, out);
}

// Round 5
// 289.574 us; speedup vs baseline: 1.1627x; 1.0287x over previous
//
#include <hip/hip_runtime.h>
#include <hip/hip_bf16.h>
#include <stdint.h>

// Problem constants
#define D_ 1024
#define H_ 16
#define DH_ 64
#define F_ 4096
#define B_ 4
#define L_ 2048
#define MTOK 8192   // B_*L_

typedef __attribute__((ext_vector_type(8))) short bf16x8;
typedef __attribute__((ext_vector_type(4))) float f32x4;

__device__ __forceinline__ short f2bf(float f) {
  uint32_t u = __float_as_uint(f);
  uint32_t r = (u + 0x7FFFu + ((u >> 16) & 1u)) >> 16;
  return (short)(uint16_t)r;
}
__device__ __forceinline__ float bf2f(short s) {
  return __uint_as_float(((uint32_t)(uint16_t)s) << 16);
}

__device__ __forceinline__ void gload_lds16(const short* g, short* l) {
  __builtin_amdgcn_global_load_lds(
      (const __attribute__((address_space(1))) void*)g,
      (__attribute__((address_space(3))) void*)l,
      16, 0, 0);
}

// ---------------- f32 -> bf16 conversion (with optional scale) ----------------
__global__ void __launch_bounds__(256) convert_bf16(
    const float* __restrict__ src, short* __restrict__ dst, long n, float scale) {
  long i = ((long)blockIdx.x * 256 + threadIdx.x) * 4;
  long stride = (long)gridDim.x * 1024;
  for (; i < n; i += stride) {
    float4 f = *(const float4*)(src + i);
    short4 o;
    o.x = f2bf(f.x * scale);
    o.y = f2bf(f.y * scale);
    o.z = f2bf(f.z * scale);
    o.w = f2bf(f.w * scale);
    *(short4*)(dst + i) = o;
  }
}

// =====================================================================
// 2-barrier-per-K-tile pipelined GEMM: C = A[M,K] @ B[N,K]^T (+bias,relu)
// BN=256, BM=BMT*128, BK=64, 8 waves (2M x 4N), per-wave (BMT*64) x 64.
// Per K-tile: phase1 { read A-h0 + B-h0 + B-h1; stage A1(g+1)->other buf;
//   lgkm0; 32 MFMA } midBAR; phase2 { read A-h1; stage B0,B1,A0(g+2)->
//   this buf; lgkm0; 32 MFMA; counted vmcnt gate } tileBAR.
// Correctness: within-phase MFMA consumes only own-wave ds_reads (lgkm0);
// midBAR separates this buf's B/A0 reads (drained in phase1) from the
// phase2 stages overwriting them; tileBAR + per-wave gate publishes the
// next tile's staged data. Gate ledger: carried {B0,B1,A0}(g+1) + A1(g+1)
// + {B0,B1,A0}(g+2) -> vmcnt(2*LB+LA) drains exactly tile g+1.
// T2 swizzle: linear LDS dest, pre-swizzled global source, swizzled read.
// T1 XCD swizzle on flat block id (grid size must be multiple of 8).
// =====================================================================
#define BAR   __builtin_amdgcn_s_barrier()
#define PRIO1 __builtin_amdgcn_s_setprio(1)
#define PRIO0 __builtin_amdgcn_s_setprio(0)
#define LGKM0 asm volatile("s_waitcnt lgkmcnt(0)" ::: "memory")

#define RD_A(mh_, par_) do {                                                  \
  const short* bp = lds + (par_) * BUF + wm * ASLOT;                          \
  _Pragma("unroll")                                                           \
  for (int m2 = 0; m2 < MH; m2++) {                                           \
    const int r = ((mh_) * MH + m2) * 16 + l15;                               \
    _Pragma("unroll")                                                         \
    for (int ks = 0; ks < 2; ks++)                                            \
      aF[mh_][m2][ks] =                                                       \
          *(const bf16x8*)(bp + r * 64 + (((ks * 4 + l4) ^ (r & 7)) << 3));   \
  } } while (0)

#define RD_B(nh_, par_) do {                                                  \
  const short* bp = lds + (par_) * BUF + BM * 64 + (wn >> 1) * 8192;          \
  _Pragma("unroll")                                                           \
  for (int n2 = 0; n2 < 2; n2++) {                                            \
    const int r = (wn & 1) * 64 + ((nh_) * 2 + n2) * 16 + l15;                \
    _Pragma("unroll")                                                         \
    for (int ks = 0; ks < 2; ks++)                                            \
      bF[nh_][n2][ks] =                                                       \
          *(const bf16x8*)(bp + r * 64 + (((ks * 4 + l4) ^ (r & 7)) << 3));   \
  } } while (0)

#define QUAD(mh_, nh_) do {                                                   \
  _Pragma("unroll")                                                           \
  for (int ks = 0; ks < 2; ks++)                                              \
    _Pragma("unroll")                                                         \
    for (int m2 = 0; m2 < MH; m2++)                                           \
      _Pragma("unroll")                                                       \
      for (int n2 = 0; n2 < 2; n2++)                                          \
        acc[(mh_) * MH + m2][(nh_) * 2 + n2] =                                \
            __builtin_amdgcn_mfma_f32_16x16x32_bf16(                          \
                aF[mh_][m2][ks], bF[nh_][n2][ks],                             \
                acc[(mh_) * MH + m2][(nh_) * 2 + n2], 0, 0, 0);               \
} while (0)

// par_ must be a literal 0/1. SN: stage A1(g+1); SPP: stage B0/B1/A0(g+2);
// GK: 1 = vmcnt(VG), 2 = vmcnt(0), 0 = none.
#define ITER2(g_, par_, SN, SPP, GK) do {                                     \
  /* phase 1 */                                                               \
  RD_A(0, par_); RD_B(0, par_); RD_B(1, par_);                                \
  if (SN) stA((g_) + 1, 1, (par_) ^ 1);                                       \
  LGKM0;                                                                      \
  PRIO1; QUAD(0, 0); QUAD(0, 1); PRIO0;                                       \
  BAR;  /* mid-tile: phase1 reads of this buf done in all waves */            \
  /* phase 2 */                                                               \
  RD_A(1, par_);                                                              \
  if (SPP) { stB((g_) + 2, 0, par_); stB((g_) + 2, 1, par_);                  \
             stA((g_) + 2, 0, par_); }                                        \
  LGKM0;                                                                      \
  PRIO1; QUAD(1, 0); QUAD(1, 1); PRIO0;                                       \
  if (GK == 1) asm volatile("s_waitcnt vmcnt(%0)" :: "i"(VG) : "memory");     \
  else if (GK == 2) asm volatile("s_waitcnt vmcnt(0)" ::: "memory");          \
  BAR;  /* tile boundary: next tile's buf published */                        \
} while (0)

template<int BMT, bool BIAS, bool RELU>
__global__ void __launch_bounds__(512, 2) gemm8p(
    const short* __restrict__ A, int lda,
    const short* __restrict__ Bm, int ldb,
    short* __restrict__ C, int ldc,
    const float* __restrict__ bias, int K) {
  constexpr int BM = BMT * 128;
  constexpr int MT = BMT * 4;            // M-frags per wave
  constexpr int MH = MT / 2;             // M-frags per quadrant
  constexpr int LA = BMT;                // per-thread loads per A-half
  constexpr int LB = 2;                  // per-thread loads per B-half
  constexpr int ASLOT = (BM / 2) * 64;   // shorts per A-half slot
  constexpr int BUF = BM * 64 + 16384;   // shorts per buffer (A + B)
  constexpr int VG = 2 * LB + LA;        // steady-state gate count

  __shared__ __align__(16) short lds[2 * BUF];

  const int tid = threadIdx.x;
  const int lane = tid & 63;
  const int wave = tid >> 6;
  const int wm = wave >> 2, wn = wave & 3;
  const int l15 = lane & 15, l4 = lane >> 4;

  // T1: XCD-aware bijective swizzle (grid size is a multiple of 8)
  const int id = blockIdx.y * gridDim.x + blockIdx.x;
  const int per = (gridDim.x * gridDim.y) >> 3;
  const int swz = (id & 7) * per + (id >> 3);
  const int bn = swz % gridDim.x;
  const int bm = swz / gridDim.x;

  const short* Ab = A + (long)bm * BM * lda;
  const short* Bb = Bm + (long)bn * 256 * ldb;
  const int NTILE = K >> 6;

  // Precomputed per-thread staging pointers: only (t<<6) is runtime.
  const short* gA[2][LA]; short* dA[2][LA];
  const short* gB[2][LB]; short* dB[2][LB];
#pragma unroll
  for (int h = 0; h < 2; h++) {
#pragma unroll
    for (int l = 0; l < LA; l++) {
      int c = l * 512 + tid, r = c >> 3, cg = (c & 7) ^ (r & 7);
      gA[h][l] = Ab + (long)(h * (BM / 2) + r) * lda + cg * 8;
      dA[h][l] = lds + h * ASLOT + c * 8;
    }
#pragma unroll
    for (int l = 0; l < LB; l++) {
      int c = l * 512 + tid, r = c >> 3, cg = (c & 7) ^ (r & 7);
      gB[h][l] = Bb + (long)(h * 128 + r) * ldb + cg * 8;
      dB[h][l] = lds + BM * 64 + h * 8192 + c * 8;
    }
  }
  auto stA = [&](int t, int h, int par) {
#pragma unroll
    for (int l = 0; l < LA; l++)
      gload_lds16(gA[h][l] + (t << 6), dA[h][l] + par * BUF);
  };
  auto stB = [&](int t, int h, int par) {
#pragma unroll
    for (int l = 0; l < LB; l++)
      gload_lds16(gB[h][l] + (t << 6), dB[h][l] + par * BUF);
  };

  f32x4 acc[MT][4];
#pragma unroll
  for (int i = 0; i < MT; i++)
#pragma unroll
    for (int j = 0; j < 4; j++) acc[i][j] = (f32x4){0.f, 0.f, 0.f, 0.f};

  bf16x8 aF[2][MH][2];   // [mh][m2][ks]
  bf16x8 bF[2][2][2];    // [nh][n2][ks]

  // prologue: tile0 fully; tile1 all but A1 (A1(t1) staged at tile0 ph1)
  stA(0, 0, 0); stA(0, 1, 0); stB(0, 0, 0); stB(0, 1, 0);
  stB(1, 0, 1); stB(1, 1, 1); stA(1, 0, 1);
  asm volatile("s_waitcnt vmcnt(%0)" :: "i"(VG) : "memory");  // tile0 landed
  BAR;

  for (int g = 0; g + 3 < NTILE; g += 2) {
    ITER2(g, 0, 1, 1, 1);
    ITER2(g + 1, 1, 1, 1, 1);
  }
  ITER2(NTILE - 2, 0, 1, 0, 2);
  ITER2(NTILE - 1, 1, 0, 0, 0);

  // epilogue: C/D layout col=lane&15, row=(lane>>4)*4+r
  const int col0 = bn * 256 + wn * 64;
  const int row0 = bm * BM + wm * (BM / 2);
#pragma unroll
  for (int nt = 0; nt < 4; nt++) {
    const int col = col0 + nt * 16 + l15;
    const float bb = BIAS ? bias[col] : 0.f;
#pragma unroll
    for (int mt = 0; mt < MT; mt++) {
      const int rbase = row0 + mt * 16 + l4 * 4;
#pragma unroll
      for (int r = 0; r < 4; r++) {
        float v = acc[mt][nt][r] + bb;
        if (RELU) v = v > 0.f ? v : 0.f;
        C[(long)(rbase + r) * ldc + col] = f2bf(v);
      }
    }
  }
}

// ---------------- simple m97-style GEMM (kept for qk & scores) ----------------
template<bool OUTF32>
__global__ void __launch_bounds__(256) gemm_bt(
    const short* __restrict__ A, int lda, long strideA,
    const short* __restrict__ Bm, int ldb, long strideB,
    void* __restrict__ Cv, int ldc, long strideC, int K) {
  const int bn = blockIdx.x;
  const int bm = blockIdx.y;
  const int bz = blockIdx.z;
  const short* Ab = A + (long)bz * strideA + (long)bm * 128 * lda;
  const short* Bb = Bm + (long)bz * strideB + (long)bn * 128 * ldb;

  __shared__ short lA[128 * 64];
  __shared__ short lB[128 * 64];

  const int tid = threadIdx.x;
  const int lane = tid & 63;
  const int wave = tid >> 6;
  const int wr = wave >> 1, wc = wave & 1;

  f32x4 acc[4][4];
#pragma unroll
  for (int i = 0; i < 4; i++)
#pragma unroll
    for (int j = 0; j < 4; j++) acc[i][j] = (f32x4){0.f, 0.f, 0.f, 0.f};

  for (int k0 = 0; k0 < K; k0 += 64) {
    __syncthreads();
#pragma unroll
    for (int i = 0; i < 4; i++) {
      int c = i * 256 + tid;
      int row = c >> 3;
      int col = (c & 7) * 8;
      gload_lds16(Ab + (long)row * lda + k0 + col, &lA[c * 8]);
      gload_lds16(Bb + (long)row * ldb + k0 + col, &lB[c * 8]);
    }
    __syncthreads();

#pragma unroll
    for (int ks = 0; ks < 2; ks++) {
      bf16x8 af[4], bfr[4];
#pragma unroll
      for (int t = 0; t < 4; t++) {
        af[t]  = *(const bf16x8*)&lA[(wr * 64 + t * 16 + (lane & 15)) * 64 + ks * 32 + (lane >> 4) * 8];
        bfr[t] = *(const bf16x8*)&lB[(wc * 64 + t * 16 + (lane & 15)) * 64 + ks * 32 + (lane >> 4) * 8];
      }
#pragma unroll
      for (int mt = 0; mt < 4; mt++)
#pragma unroll
        for (int nt = 0; nt < 4; nt++)
          acc[mt][nt] = __builtin_amdgcn_mfma_f32_16x16x32_bf16(af[mt], bfr[nt], acc[mt][nt], 0, 0, 0);
    }
  }

  const int col0 = bn * 128 + wc * 64;
  const int row0 = bm * 128 + wr * 64;
#pragma unroll
  for (int mt = 0; mt < 4; mt++) {
#pragma unroll
    for (int nt = 0; nt < 4; nt++) {
      int col = col0 + nt * 16 + (lane & 15);
      int rbase = row0 + mt * 16 + (lane >> 4) * 4;
#pragma unroll
      for (int r = 0; r < 4; r++) {
        float v = acc[mt][nt][r];
        long off = (long)bz * strideC + (long)(rbase + r) * ldc + col;
        if (OUTF32) ((float*)Cv)[off] = v;
        else        ((short*)Cv)[off] = f2bf(v);
      }
    }
  }
}

// ---------------- reductions ----------------
__device__ __forceinline__ float wave_sum(float v) {
#pragma unroll
  for (int o = 32; o > 0; o >>= 1) v += __shfl_xor(v, o, 64);
  return v;
}
__device__ __forceinline__ float wave_max(float v) {
#pragma unroll
  for (int o = 32; o > 0; o >>= 1) v = fmaxf(v, __shfl_xor(v, o, 64));
  return v;
}

// ---------------- in-place row softmax over 2048 cols, then /H ----------------
__global__ void __launch_bounds__(256) softmax_div16(float* __restrict__ s) {
  const int tid = threadIdx.x;
  float* p = s + (long)blockIdx.x * 2048;
  float4 a = *(const float4*)(p + tid * 8);
  float4 b = *(const float4*)(p + tid * 8 + 4);
  float m = fmaxf(fmaxf(fmaxf(a.x, a.y), fmaxf(a.z, a.w)),
                  fmaxf(fmaxf(b.x, b.y), fmaxf(b.z, b.w)));
  __shared__ float red[4];
  m = wave_max(m);
  if ((tid & 63) == 0) red[tid >> 6] = m;
  __syncthreads();
  m = fmaxf(fmaxf(red[0], red[1]), fmaxf(red[2], red[3]));

  float e0 = __expf(a.x - m), e1 = __expf(a.y - m), e2 = __expf(a.z - m), e3 = __expf(a.w - m);
  float e4 = __expf(b.x - m), e5 = __expf(b.y - m), e6 = __expf(b.z - m), e7 = __expf(b.w - m);
  float sum = (e0 + e1) + (e2 + e3) + ((e4 + e5) + (e6 + e7));
  __syncthreads();
  sum = wave_sum(sum);
  if ((tid & 63) == 0) red[tid >> 6] = sum;
  __syncthreads();
  sum = red[0] + red[1] + red[2] + red[3];
  float inv = 1.0f / (sum * 16.0f);
  a.x = e0 * inv; a.y = e1 * inv; a.z = e2 * inv; a.w = e3 * inv;
  b.x = e4 * inv; b.y = e5 * inv; b.z = e6 * inv; b.w = e7 * inv;
  *(float4*)(p + tid * 8) = a;
  *(float4*)(p + tid * 8 + 4) = b;
}

// ---------------- fused residual + LayerNorm (f32 out) ----------------
__global__ void __launch_bounds__(256) ln_fuse(
    const short* __restrict__ ctx, const short* __restrict__ ffn,
    const float* __restrict__ g, const float* __restrict__ bta,
    float* __restrict__ out) {
  const int tid = threadIdx.x;
  long base = (long)blockIdx.x * 1024 + tid * 4;
  short4 c4 = *(const short4*)(ctx + base);
  short4 f4 = *(const short4*)(ffn + base);
  float x0 = bf2f(c4.x) + bf2f(f4.x);
  float x1 = bf2f(c4.y) + bf2f(f4.y);
  float x2 = bf2f(c4.z) + bf2f(f4.z);
  float x3 = bf2f(c4.w) + bf2f(f4.w);

  float s = (x0 + x1) + (x2 + x3);
  float q = (x0 * x0 + x1 * x1) + (x2 * x2 + x3 * x3);
  __shared__ float rs[4], rq[4];
  s = wave_sum(s);
  q = wave_sum(q);
  if ((tid & 63) == 0) { rs[tid >> 6] = s; rq[tid >> 6] = q; }
  __syncthreads();
  float S = rs[0] + rs[1] + rs[2] + rs[3];
  float Q = rq[0] + rq[1] + rq[2] + rq[3];
  float mu = S * (1.0f / 1024.0f);
  float var = Q * (1.0f / 1024.0f) - mu * mu;
  float inv = rsqrtf(var + 1e-5f);

  float4 g4 = *(const float4*)(g + tid * 4);
  float4 b4 = *(const float4*)(bta + tid * 4);
  float4 o;
  o.x = (x0 - mu) * inv * g4.x + b4.x;
  o.y = (x1 - mu) * inv * g4.y + b4.y;
  o.z = (x2 - mu) * inv * g4.z + b4.z;
  o.w = (x3 - mu) * inv * g4.w + b4.w;
  *(float4*)(out + base) = o;
}

// ---------------- launch ----------------
extern "C" void kernel_launch(void* const* d_in, const int* in_sizes, int n_in,
                              void* d_out, int out_size, void* d_ws, size_t ws_size,
                              hipStream_t stream) {
  const float* inputs = (const float*)d_in[0];
  const float* Wq = (const float*)d_in[1];
  const float* Wk = (const float*)d_in[2];
  const float* Wv = (const float*)d_in[3];
  const float* Wo = (const float*)d_in[4];
  const float* W1 = (const float*)d_in[5];
  const float* b1 = (const float*)d_in[6];
  const float* W2 = (const float*)d_in[7];
  const float* b2 = (const float*)d_in[8];
  const float* ln_g = (const float*)d_in[9];
  const float* ln_b = (const float*)d_in[10];

  char* w = (char*)d_ws;
  short* in_bf = (short*)w;  w += (long)MTOK * D_ * 2;
  short* wqk   = (short*)w;  w += 128L * D_ * 2;
  short* wv    = (short*)w;  w += (long)D_ * D_ * 2;
  short* wo    = (short*)w;  w += (long)D_ * D_ * 2;
  short* w1    = (short*)w;  w += (long)F_ * D_ * 2;
  short* w2    = (short*)w;  w += (long)D_ * F_ * 2;
  short* qkh   = (short*)w;  w += (long)MTOK * 128 * 2;
  short* vbf   = (short*)w;  w += (long)MTOK * D_ * 2;
  short* ctxbf = (short*)w;  w += (long)MTOK * D_ * 2;
  short* hbf   = (short*)w;  w += (long)MTOK * F_ * 2;
  short* ffnbf = (short*)w;  w += (long)MTOK * D_ * 2;

  float* out  = (float*)d_out;                 // [8192][1024]
  float* attn = out + (long)MTOK * D_;         // [4][2048][2048]

  const float scale = 0.125f;  // DH^-0.5

  convert_bf16<<<dim3((MTOK * D_) >> 10), 256, 0, stream>>>(inputs, in_bf, (long)MTOK * D_, 1.0f);
  convert_bf16<<<dim3((64 * D_) >> 10), 256, 0, stream>>>(Wq + 960 * D_, wqk, 64L * D_, scale);
  convert_bf16<<<dim3((64 * D_) >> 10), 256, 0, stream>>>(Wk + 960 * D_, wqk + 64L * D_, 64L * D_, 1.0f);
  convert_bf16<<<dim3((D_ * D_) >> 10), 256, 0, stream>>>(Wv, wv, (long)D_ * D_, 1.0f);
  convert_bf16<<<dim3((D_ * D_) >> 10), 256, 0, stream>>>(Wo, wo, (long)D_ * D_, 1.0f);
  convert_bf16<<<dim3((F_ * D_) >> 10), 256, 0, stream>>>(W1, w1, (long)F_ * D_, 1.0f);
  convert_bf16<<<dim3((F_ * D_) >> 10), 256, 0, stream>>>(W2, w2, (long)F_ * D_, 1.0f);

  // qH|kH = inputs @ wqk^T   (M=8192, N=128, K=1024) — small, m97 kernel
  gemm_bt<false><<<dim3(1, 64, 1), 256, 0, stream>>>(
      in_bf, D_, 0, wqk, D_, 0, qkh, 128, 0, D_);
  // v = inputs @ Wv^T        (M=8192, N=1024, K=1024) — pipelined, 128x256
  gemm8p<1, false, false><<<dim3(4, 64), 512, 0, stream>>>(
      in_bf, D_, wv, D_, vbf, D_, nullptr, D_);
  // scores[b] = qH @ kH^T    (M=2048, N=2048, K=64, batch=4) -> attn (f32)
  gemm_bt<true><<<dim3(16, 16, 4), 256, 0, stream>>>(
      qkh, 128, (long)L_ * 128, qkh + 64, 128, (long)L_ * 128,
      attn, L_, (long)L_ * L_, 64);
  // softmax rows (in place) + /H
  softmax_div16<<<dim3(MTOK), 256, 0, stream>>>(attn);
  // context = v @ Wo^T       (M=8192, N=1024, K=1024) — pipelined, 128x256
  gemm8p<1, false, false><<<dim3(4, 64), 512, 0, stream>>>(
      vbf, D_, wo, D_, ctxbf, D_, nullptr, D_);
  // h = relu(ctx @ W1^T + b1) (M=8192, N=4096, K=1024) — pipelined, 256x256
  gemm8p<2, true, true><<<dim3(16, 32), 512, 0, stream>>>(
      ctxbf, D_, w1, D_, hbf, F_, b1, D_);
  // ffn = h @ W2^T + b2       (M=8192, N=1024, K=4096) — pipelined, 128x256
  gemm8p<1, true, false><<<dim3(4, 64), 512, 0, stream>>>(
      hbf, F_, w2, F_, ffnbf, D_, b2, F_);
  // out = LN(ctx + ffn)
  ln_fuse<<<dim3(MTOK), 256, 0, stream>>>(ctxbf, ffnbf, ln_g, ln_b, out);
}